// Round 1
// 93.408 us; speedup vs baseline: 1.0946x; 1.0946x over previous
//
#include <hip/hip_runtime.h>
#include <math.h>

// Problem constants (fixed by reference setup_inputs)
#define HH 512
#define WW 1024
#define HW (HH*WW)
#define TOPK 200
#define NMSPAD 3            // (7-1)/2
#define THRESH 0.1f
#define NBINS 4096          // LDS histogram bins (16 KB); binning exact for any count
#define SUBCAP 1024         // suffix-subset capacity (expected m ~ 205)
#define CACHECAP 12288      // LDS candidate cache (96 KB); expected V ~ 10.7K (HW/49)
#define SLOTS 24            // per-block candidate slots; 7x7-NMS max for 32x8 is 16
#define NBX 32              // grid x of k1 (WW/32)
#define NBY 64              // grid y of k1 (HH/8)
#define NB (NBX*NBY)        // 2048 blocks

// ---------------- helpers ----------------
__device__ __forceinline__ int score_bin(float s) {
    // monotone non-decreasing binning of scores in (0.1, 1]
    int b = (int)((s - THRESH) * (float)(NBINS / 0.9f));
    if (b < 0) b = 0;
    if (b > NBINS - 1) b = NBINS - 1;
    return b;
}

// ---------------- K1: threshold + 7x7 NMS -> per-block candidate lists ------
// Per-block LDS compaction; NO same-address global atomics (R1 post-mortem:
// one global counter serialized ~8192 wave-atomics -> 76 us).
// R6: (score,idx) packed into one int2 so k3 pays one load round, not two.
__global__ __launch_bounds__(256) void k1_nms(const float* __restrict__ hmp,
                                              int* __restrict__ blkcnt,
                                              int2* __restrict__ blkpair) {
    const int BX = 32, BY = 8, TW = BX + 6, TH = BY + 6;
    __shared__ float A[TH][TW + 2];   // stride 40 breaks pow2 bank stride
    __shared__ float R[TH][BX];
    __shared__ float lsc[SLOTS];
    __shared__ int   lid[SLOTS];
    __shared__ int   s_cnt;
    int lx = threadIdx.x, ly = threadIdx.y;
    int x0 = blockIdx.x * BX, y0 = blockIdx.y * BY;
    int tid = ly * BX + lx;
    if (tid == 0) s_cnt = 0;

    for (int t = tid; t < TH * TW; t += 256) {
        int r = t / TW, c = t % TW;
        int gy = y0 - NMSPAD + r, gx = x0 - NMSPAD + c;
        float v = -INFINITY;  // reduce_window pads with init = -inf
        if (gy >= 0 && gy < HH && gx >= 0 && gx < WW) {
            float h = hmp[gy * WW + gx];
            v = (h > THRESH) ? h : -1.0f;
        }
        A[r][c] = v;
    }
    __syncthreads();
    for (int t = tid; t < TH * BX; t += 256) {
        int r = t / BX, c = t % BX;
        float m = A[r][c];
        #pragma unroll
        for (int d = 1; d < 7; ++d) m = fmaxf(m, A[r][c + d]);
        R[r][c] = m;
    }
    __syncthreads();
    float v = A[ly + NMSPAD][lx + NMSPAD];
    if (v > 0.0f) {                       // thresholded candidate
        float m = R[ly][lx];
        #pragma unroll
        for (int d = 1; d < 7; ++d) m = fmaxf(m, R[ly + d][lx]);
        if (v == m) {                     // local max (ties kept, like ref)
            int p = atomicAdd(&s_cnt, 1); // LDS atomic: ~5/block, cheap
            if (p < SLOTS) { lsc[p] = v; lid[p] = (y0 + ly) * WW + (x0 + lx); }
        }
    }
    __syncthreads();
    int b = blockIdx.y * NBX + blockIdx.x;
    int cnt = min(s_cnt, SLOTS);
    if (tid == 0) blkcnt[b] = cnt;
    if (tid < cnt)
        blkpair[b * SLOTS + tid] = make_int2(__float_as_int(lsc[tid]), lid[tid]);
}

// ---------------- K3: exact top-K selection + ordering (single block) --------
// R6 rework (latency/serial-section fixes; selection semantics unchanged):
//  * shuffle-based block prefix scans replace (a) the tid0 serial 1024-chunk
//    cutoff walk and (b) the 1024 same-address s_V LDS atomics,
//  * all candidates cached in LDS during pass 1 (deterministic slots from the
//    blkcnt prefix scan -> no compaction atomics); pass 2 is LDS-local,
//  * exact global fallback if V > CACHECAP (never for this input, V ~ 10.7K).
// Output rows = valid centers sorted by flat idx (matches argsort(order_key));
// V<K tail = lowest non-candidate indices. Exact under ANY binning: cb is the
// bin of the K-th largest, subset {bin >= cb} provably contains the top-K.
__global__ __launch_bounds__(1024) void k3_select(const int* __restrict__ blkcnt,
                                                  const int2* __restrict__ blkpair,
                                                  int* __restrict__ out_center,
                                                  int* __restrict__ out_valid,
                                                  float2* __restrict__ ctr2) {
    __shared__ int   hist[NBINS];     // 16 KB
    __shared__ float cs[CACHECAP];    // 48 KB  candidate scores
    __shared__ int   ci[CACHECAP];    // 48 KB  candidate flat indices
    __shared__ float ss[SUBCAP];      // 4 KB
    __shared__ int   sidx[SUBCAP];    // 4 KB
    __shared__ int   srank[SUBCAP];   // 4 KB
    __shared__ int   sselidx[TOPK];
    __shared__ int   sb[64];          // scan temps
    __shared__ int   s_cb, s_m, s_ovf, s_T0, s_V;
    int tid = threadIdx.x;
    int lane = tid & 63, wid = tid >> 6;

    #pragma unroll
    for (int i = 0; i < NBINS / 1024; ++i) hist[tid + i * 1024] = 0;
    if (tid == 0) { s_m = 0; s_ovf = 0; s_cb = 0; }

    // ---- scan 1: exclusive prefix over the 2048 per-block counts ----------
    // thread t owns k1-blocks t and t+1024; cache layout = [candidates of
    // blocks 0..1023][candidates of blocks 1024..2047] (order irrelevant)
    int c0 = blkcnt[tid];
    int c1 = blkcnt[tid + 1024];
    int v0 = c0, v1 = c1;
    #pragma unroll
    for (int off = 1; off < 64; off <<= 1) {
        int u0 = __shfl_up(v0, off, 64);
        int u1 = __shfl_up(v1, off, 64);
        if (lane >= off) { v0 += u0; v1 += u1; }
    }
    if (lane == 63) { sb[wid] = v0; sb[16 + wid] = v1; }
    __syncthreads();
    if (tid < 16) {
        int w0 = sb[tid], w1 = sb[16 + tid];
        int a0 = w0, a1 = w1;
        #pragma unroll
        for (int off = 1; off < 16; off <<= 1) {
            int u0 = __shfl_up(a0, off, 64);
            int u1 = __shfl_up(a1, off, 64);
            if (lane >= off) { a0 += u0; a1 += u1; }
        }
        sb[32 + tid] = a0 - w0;       // exclusive wave base, first 1024 blocks
        sb[48 + tid] = a1 - w1;       // exclusive wave base, second 1024 blocks
        if (tid == 15) { s_T0 = a0; s_V = a0 + a1; }
    }
    __syncthreads();
    int off0 = sb[32 + wid] + v0 - c0;
    int off1 = s_T0 + sb[48 + wid] + v1 - c1;
    int V = s_V;

    // ---- pass 1: fill LDS cache + histogram (one 8B load per candidate) ---
    for (int rep = 0; rep < 2; ++rep) {
        int b   = rep ? tid + 1024 : tid;
        int cnt = rep ? c1 : c0;
        int off = rep ? off1 : off0;
        for (int s = 0; s < cnt; ++s) {
            int2 pr = blkpair[b * SLOTS + s];
            float sc = __int_as_float(pr.x);
            atomicAdd(&hist[score_bin(sc)], 1);   // scattered bins, light
            int p = off + s;
            if (p < CACHECAP) { cs[p] = sc; ci[p] = pr.y; }
            else s_ovf = 1;                        // benign race (writes 1)
        }
    }
    __syncthreads();

    // ---- scan 2: parallel cutoff (bin of the K-th largest score) ----------
    int base = tid * (NBINS / 1024);
    int csum = 0;
    #pragma unroll
    for (int i = 0; i < NBINS / 1024; ++i) csum += hist[base + i];
    int vc = csum;
    #pragma unroll
    for (int off = 1; off < 64; off <<= 1) {
        int u = __shfl_up(vc, off, 64);
        if (lane >= off) vc += u;
    }
    if (lane == 63) sb[wid] = vc;
    __syncthreads();
    if (tid < 16) {
        int w = sb[tid]; int a = w;
        #pragma unroll
        for (int off = 1; off < 16; off <<= 1) {
            int u = __shfl_up(a, off, 64);
            if (lane >= off) a += u;
        }
        sb[32 + tid] = a - w;
    }
    __syncthreads();
    int pexcl = sb[32 + wid] + vc - csum;  // sum of chunks below this one
    int S = V - pexcl;                     // suffix sum incl. own chunk
    if (S >= TOPK && S - csum < TOPK) {    // unique crossing thread (if V>=K)
        int acc = S - csum;
        for (int bb = base + NBINS / 1024 - 1; bb >= base; --bb) {
            acc += hist[bb];
            if (acc >= TOPK) { s_cb = bb; break; }
        }
    }
    __syncthreads();
    int cb = s_cb;                         // stays 0 if V < K -> keep all

    // ---- pass 2: gather suffix subset (LDS-local; global fallback exact) --
    if (!s_ovf) {
        for (int i = tid; i < V; i += 1024) {
            float sc = cs[i];
            if (score_bin(sc) >= cb) {
                int p = atomicAdd(&s_m, 1);
                if (p < SUBCAP) { ss[p] = sc; sidx[p] = ci[i]; }
            }
        }
    } else {
        for (int rep = 0; rep < 2; ++rep) {
            int b   = rep ? tid + 1024 : tid;
            int cnt = rep ? c1 : c0;
            for (int s = 0; s < cnt; ++s) {
                int2 pr = blkpair[b * SLOTS + s];
                float sc = __int_as_float(pr.x);
                if (score_bin(sc) >= cb) {
                    int p = atomicAdd(&s_m, 1);
                    if (p < SUBCAP) { ss[p] = sc; sidx[p] = pr.y; }
                }
            }
        }
    }
    __syncthreads();
    int m = min(s_m, SUBCAP);

    // exact rank (top_k order) within subset
    for (int i = tid; i < m; i += 1024) {
        float si = ss[i]; int ii = sidx[i]; int r = 0;
        for (int j = 0; j < m; ++j) {
            float sj = ss[j];
            r += (sj > si) || (sj == si && sidx[j] < ii);
        }
        srank[i] = r;
    }
    __syncthreads();

    // selected (rank < K): output position = order by flat idx among selected
    for (int i = tid; i < m; i += 1024) {
        if (srank[i] < TOPK) {
            int ii = sidx[i];
            int pos = 0;
            for (int j = 0; j < m; ++j)
                pos += (srank[j] < TOPK) && (sidx[j] < ii);
            int y = ii >> 10, x = ii & (WW - 1);
            out_center[2 * pos] = y;
            out_center[2 * pos + 1] = x;
            out_valid[pos] = 1;
            ctr2[pos] = make_float2((float)y, (float)x);
            sselidx[pos] = ii;
        }
    }
    __syncthreads();

    // V < K tail: lowest non-candidate flat indices, invalid
    if (tid == 0 && V < TOPK) {
        int slot = V, t = 0, p = 0;
        while (slot < TOPK) {
            if (p < V && t == sselidx[p]) { t++; p++; }
            else {
                out_center[2 * slot] = t >> 10;
                out_center[2 * slot + 1] = t & (WW - 1);
                out_valid[slot] = 0;
                ctr2[slot] = make_float2(1e10f, 1e10f);
                t++; slot++;
            }
        }
    }
}

// ---------------- K4: nearest-center assignment + thing mask ----------------
// Exact-safe pruning, R5: iterate the wave-uniform keep-MASK bits instead of
// the contiguous [ka,kb) superset (~40 vs ~70 centers). Proof sketch: for a
// skipped center k, lb_k > ub >= best_final(p) for every pixel p in the wave,
// and lb_k <= d2(p,k) by monotonicity of round-to-nearest, so d2(p,k) > best
// STRICTLY -> cannot win nor tie. Kept centers are visited in ascending k
// (r-chunks ascending, ctz ascending), and the body is op-for-op identical to
// the reference (__f*_rn, no fma contraction) -> bit-exact argmin + tie order.
__global__ __launch_bounds__(256) void k4_assign(const int* __restrict__ sem,
                                                 const float* __restrict__ off,
                                                 const float2* __restrict__ ctr2,
                                                 int* __restrict__ out_inst) {
    __shared__ float2 c[TOPK];
    int tid = threadIdx.x;
    if (tid < TOPK) c[tid] = ctr2[tid];
    __syncthreads();

    int p = blockIdx.x * 256 + tid;
    int y = p >> 10, x = p & (WW - 1);
    int s = sem[p];                                // hoist: overlap latency
    float ly = __fadd_rn((float)y, off[p]);        // offsets[0,0]
    float lx = __fadd_rn((float)x, off[HW + p]);   // offsets[0,1]

    // wave bbox of (ly,lx) — min/max are exact, no rounding introduced
    float ymin = ly, ymax = ly, xmin = lx, xmax = lx;
    #pragma unroll
    for (int mdist = 32; mdist >= 1; mdist >>= 1) {
        ymin = fminf(ymin, __shfl_xor(ymin, mdist, 64));
        ymax = fmaxf(ymax, __shfl_xor(ymax, mdist, 64));
        xmin = fminf(xmin, __shfl_xor(xmin, mdist, 64));
        xmax = fmaxf(xmax, __shfl_xor(xmax, mdist, 64));
    }

    int lane = tid & 63;
    float ub = INFINITY;
    float lbv[4];
    // lane covers centers k = r*64 + lane
    #pragma unroll
    for (int r = 0; r < 4; ++r) {
        int k = r * 64 + lane;
        float lb = INFINITY;
        float u = INFINITY;
        if (k < TOPK) {
            float2 ck = c[k];
            // far-corner bound: dyM >= |rn(cy - ly)| for all ly in [ymin,ymax]
            float dyM = fmaxf(__fsub_rn(ck.x, ymin), __fsub_rn(ymax, ck.x));
            float dxM = fmaxf(__fsub_rn(ck.y, xmin), __fsub_rn(xmax, ck.y));
            u = __fadd_rn(__fmul_rn(dyM, dyM), __fmul_rn(dxM, dxM));
            // near-corner bound: dyL <= |rn(cy - ly)| for all ly in [ymin,ymax]
            float dyL = fmaxf(0.0f, fmaxf(__fsub_rn(ck.x, ymax), __fsub_rn(ymin, ck.x)));
            float dxL = fmaxf(0.0f, fmaxf(__fsub_rn(ck.y, xmax), __fsub_rn(xmin, ck.y)));
            lb = __fadd_rn(__fmul_rn(dyL, dyL), __fmul_rn(dxL, dxL));
        }
        ub = fminf(ub, u);
        lbv[r] = lb;
    }
    #pragma unroll
    for (int mdist = 32; mdist >= 1; mdist >>= 1)
        ub = fminf(ub, __shfl_xor(ub, mdist, 64));

    // wave-uniform keep masks (bit lane of km[r] = keep center r*64+lane)
    unsigned long long km[4];
    #pragma unroll
    for (int r = 0; r < 4; ++r) km[r] = __ballot(lbv[r] <= ub);
    if (!(km[0] | km[1] | km[2] | km[3])) {        // safety net; unreachable
        km[0] = km[1] = km[2] = ~0ull; km[3] = 0xFFull;
    }

    float best = INFINITY;
    int bid = 0;
    #pragma unroll
    for (int r = 0; r < 4; ++r) {
        unsigned long long msk = km[r];
        while (msk) {                              // uniform flow, ascending k
            int k = r * 64 + __builtin_ctzll(msk);
            msk &= msk - 1;
            float2 ck = c[k];                      // uniform k -> LDS broadcast
            float dy = __fsub_rn(ck.x, ly);
            float dx = __fsub_rn(ck.y, lx);
            float d2 = __fadd_rn(__fmul_rn(dy, dy), __fmul_rn(dx, dx));
            if (d2 < best) { best = d2; bid = k; } // strict < = first-occurrence
        }
    }
    unsigned t = (unsigned)(s - 11);               // THING_LIST = 11..18
    out_inst[p] = (t <= 7u) ? (bid + 1) : 0;
}

// ---------------- launch ----------------
extern "C" void kernel_launch(void* const* d_in, const int* in_sizes, int n_in,
                              void* d_out, int out_size, void* d_ws, size_t ws_size,
                              hipStream_t stream) {
    const int* sem = (const int*)d_in[0];
    const float* hmp = (const float*)d_in[1];
    const float* off = (const float*)d_in[2];
    int* out = (int*)d_out;

    // workspace layout (~394 KB)
    char* ws = (char*)d_ws;
    int* blkcnt   = (int*)(ws);                       // 8 KB
    int2* blkpair = (int2*)(ws + 8192);               // 384 KB (score,idx)
    float2* ctr2  = (float2*)(ws + 8192 + 393216);    // 1.6 KB

    int* out_inst = out;                   // [1,H,W] int32
    int* out_center = out + HW;            // [1,K,2] int32 (y,x)
    int* out_valid = out + HW + 2 * TOPK;  // [K] 0/1

    k1_nms<<<dim3(NBX, NBY), dim3(32, 8), 0, stream>>>(hmp, blkcnt, blkpair);
    k3_select<<<1, 1024, 0, stream>>>(blkcnt, blkpair,
                                      out_center, out_valid, ctr2);
    k4_assign<<<HW / 256, 256, 0, stream>>>(sem, off, ctr2, out_inst);
}

// Round 2
// 92.762 us; speedup vs baseline: 1.1022x; 1.0070x over previous
//
#include <hip/hip_runtime.h>
#include <math.h>

// Problem constants (fixed by reference setup_inputs)
#define HH 512
#define WW 1024
#define HW (HH*WW)
#define TOPK 200
#define NMSPAD 3            // (7-1)/2
#define THRESH 0.1f
#define NBINS 4096          // LDS histogram bins (16 KB); binning exact for any count
#define SUBCAP 1024         // suffix-subset capacity (expected m ~ 205)
#define CACHECAP 12288      // LDS candidate cache (96 KB); expected V ~ 10.7K (HW/49)
#define SLOTS 24            // per-block candidate slots; 7x7-NMS max for 32x8 is 16
#define NBX 32              // grid x of k1 (WW/32)
#define NBY 64              // grid y of k1 (HH/8)
#define NB (NBX*NBY)        // 2048 blocks

// ---------------- helpers ----------------
__device__ __forceinline__ int score_bin(float s) {
    // monotone non-decreasing binning of scores in (0.1, 1]
    int b = (int)((s - THRESH) * (float)(NBINS / 0.9f));
    if (b < 0) b = 0;
    if (b > NBINS - 1) b = NBINS - 1;
    return b;
}

// ---------------- K1: threshold + 7x7 NMS -> per-block candidate lists ------
// Per-block LDS compaction; NO same-address global atomics (R1 post-mortem:
// one global counter serialized ~8192 wave-atomics -> 76 us).
// R6: (score,idx) packed into one int2 so k3 pays one load round, not two.
__global__ __launch_bounds__(256) void k1_nms(const float* __restrict__ hmp,
                                              int* __restrict__ blkcnt,
                                              int2* __restrict__ blkpair) {
    const int BX = 32, BY = 8, TW = BX + 6, TH = BY + 6;
    __shared__ float A[TH][TW + 2];   // stride 40 breaks pow2 bank stride
    __shared__ float R[TH][BX];
    __shared__ float lsc[SLOTS];
    __shared__ int   lid[SLOTS];
    __shared__ int   s_cnt;
    int lx = threadIdx.x, ly = threadIdx.y;
    int x0 = blockIdx.x * BX, y0 = blockIdx.y * BY;
    int tid = ly * BX + lx;
    if (tid == 0) s_cnt = 0;

    for (int t = tid; t < TH * TW; t += 256) {
        int r = t / TW, c = t % TW;
        int gy = y0 - NMSPAD + r, gx = x0 - NMSPAD + c;
        float v = -INFINITY;  // reduce_window pads with init = -inf
        if (gy >= 0 && gy < HH && gx >= 0 && gx < WW) {
            float h = hmp[gy * WW + gx];
            v = (h > THRESH) ? h : -1.0f;
        }
        A[r][c] = v;
    }
    __syncthreads();
    for (int t = tid; t < TH * BX; t += 256) {
        int r = t / BX, c = t % BX;
        float m = A[r][c];
        #pragma unroll
        for (int d = 1; d < 7; ++d) m = fmaxf(m, A[r][c + d]);
        R[r][c] = m;
    }
    __syncthreads();
    float v = A[ly + NMSPAD][lx + NMSPAD];
    if (v > 0.0f) {                       // thresholded candidate
        float m = R[ly][lx];
        #pragma unroll
        for (int d = 1; d < 7; ++d) m = fmaxf(m, R[ly + d][lx]);
        if (v == m) {                     // local max (ties kept, like ref)
            int p = atomicAdd(&s_cnt, 1); // LDS atomic: ~5/block, cheap
            if (p < SLOTS) { lsc[p] = v; lid[p] = (y0 + ly) * WW + (x0 + lx); }
        }
    }
    __syncthreads();
    int b = blockIdx.y * NBX + blockIdx.x;
    int cnt = min(s_cnt, SLOTS);
    if (tid == 0) blkcnt[b] = cnt;
    if (tid < cnt)
        blkpair[b * SLOTS + tid] = make_int2(__float_as_int(lsc[tid]), lid[tid]);
}

// ---------------- K3: exact top-K selection + ordering (single block) --------
// R6 structure (verified, 8.8 us win): shuffle-based block prefix scans, full
// LDS candidate cache with deterministic slots, exact global fallback.
// Output rows = valid centers sorted by flat idx (matches argsort(order_key));
// V<K tail = lowest non-candidate indices. Exact under ANY binning: cb is the
// bin of the K-th largest, subset {bin >= cb} provably contains the top-K.
__global__ __launch_bounds__(1024) void k3_select(const int* __restrict__ blkcnt,
                                                  const int2* __restrict__ blkpair,
                                                  int* __restrict__ out_center,
                                                  int* __restrict__ out_valid,
                                                  float2* __restrict__ ctr2) {
    __shared__ int   hist[NBINS];     // 16 KB
    __shared__ float cs[CACHECAP];    // 48 KB  candidate scores
    __shared__ int   ci[CACHECAP];    // 48 KB  candidate flat indices
    __shared__ float ss[SUBCAP];      // 4 KB
    __shared__ int   sidx[SUBCAP];    // 4 KB
    __shared__ int   srank[SUBCAP];   // 4 KB
    __shared__ int   sselidx[TOPK];
    __shared__ int   sb[64];          // scan temps
    __shared__ int   s_cb, s_m, s_ovf, s_T0, s_V;
    int tid = threadIdx.x;
    int lane = tid & 63, wid = tid >> 6;

    #pragma unroll
    for (int i = 0; i < NBINS / 1024; ++i) hist[tid + i * 1024] = 0;
    if (tid == 0) { s_m = 0; s_ovf = 0; s_cb = 0; }

    // ---- scan 1: exclusive prefix over the 2048 per-block counts ----------
    // thread t owns k1-blocks t and t+1024; cache layout = [candidates of
    // blocks 0..1023][candidates of blocks 1024..2047] (order irrelevant)
    int c0 = blkcnt[tid];
    int c1 = blkcnt[tid + 1024];
    int v0 = c0, v1 = c1;
    #pragma unroll
    for (int off = 1; off < 64; off <<= 1) {
        int u0 = __shfl_up(v0, off, 64);
        int u1 = __shfl_up(v1, off, 64);
        if (lane >= off) { v0 += u0; v1 += u1; }
    }
    if (lane == 63) { sb[wid] = v0; sb[16 + wid] = v1; }
    __syncthreads();
    if (tid < 16) {
        int w0 = sb[tid], w1 = sb[16 + tid];
        int a0 = w0, a1 = w1;
        #pragma unroll
        for (int off = 1; off < 16; off <<= 1) {
            int u0 = __shfl_up(a0, off, 64);
            int u1 = __shfl_up(a1, off, 64);
            if (lane >= off) { a0 += u0; a1 += u1; }
        }
        sb[32 + tid] = a0 - w0;       // exclusive wave base, first 1024 blocks
        sb[48 + tid] = a1 - w1;       // exclusive wave base, second 1024 blocks
        if (tid == 15) { s_T0 = a0; s_V = a0 + a1; }
    }
    __syncthreads();
    int off0 = sb[32 + wid] + v0 - c0;
    int off1 = s_T0 + sb[48 + wid] + v1 - c1;
    int V = s_V;

    // ---- pass 1: fill LDS cache + histogram (one 8B load per candidate) ---
    for (int rep = 0; rep < 2; ++rep) {
        int b   = rep ? tid + 1024 : tid;
        int cnt = rep ? c1 : c0;
        int off = rep ? off1 : off0;
        for (int s = 0; s < cnt; ++s) {
            int2 pr = blkpair[b * SLOTS + s];
            float sc = __int_as_float(pr.x);
            atomicAdd(&hist[score_bin(sc)], 1);   // scattered bins, light
            int p = off + s;
            if (p < CACHECAP) { cs[p] = sc; ci[p] = pr.y; }
            else s_ovf = 1;                        // benign race (writes 1)
        }
    }
    __syncthreads();

    // ---- scan 2: parallel cutoff (bin of the K-th largest score) ----------
    int base = tid * (NBINS / 1024);
    int csum = 0;
    #pragma unroll
    for (int i = 0; i < NBINS / 1024; ++i) csum += hist[base + i];
    int vc = csum;
    #pragma unroll
    for (int off = 1; off < 64; off <<= 1) {
        int u = __shfl_up(vc, off, 64);
        if (lane >= off) vc += u;
    }
    if (lane == 63) sb[wid] = vc;
    __syncthreads();
    if (tid < 16) {
        int w = sb[tid]; int a = w;
        #pragma unroll
        for (int off = 1; off < 16; off <<= 1) {
            int u = __shfl_up(a, off, 64);
            if (lane >= off) a += u;
        }
        sb[32 + tid] = a - w;
    }
    __syncthreads();
    int pexcl = sb[32 + wid] + vc - csum;  // sum of chunks below this one
    int S = V - pexcl;                     // suffix sum incl. own chunk
    if (S >= TOPK && S - csum < TOPK) {    // unique crossing thread (if V>=K)
        int acc = S - csum;
        for (int bb = base + NBINS / 1024 - 1; bb >= base; --bb) {
            acc += hist[bb];
            if (acc >= TOPK) { s_cb = bb; break; }
        }
    }
    __syncthreads();
    int cb = s_cb;                         // stays 0 if V < K -> keep all

    // ---- pass 2: gather suffix subset (LDS-local; global fallback exact) --
    if (!s_ovf) {
        for (int i = tid; i < V; i += 1024) {
            float sc = cs[i];
            if (score_bin(sc) >= cb) {
                int p = atomicAdd(&s_m, 1);
                if (p < SUBCAP) { ss[p] = sc; sidx[p] = ci[i]; }
            }
        }
    } else {
        for (int rep = 0; rep < 2; ++rep) {
            int b   = rep ? tid + 1024 : tid;
            int cnt = rep ? c1 : c0;
            for (int s = 0; s < cnt; ++s) {
                int2 pr = blkpair[b * SLOTS + s];
                float sc = __int_as_float(pr.x);
                if (score_bin(sc) >= cb) {
                    int p = atomicAdd(&s_m, 1);
                    if (p < SUBCAP) { ss[p] = sc; sidx[p] = pr.y; }
                }
            }
        }
    }
    __syncthreads();
    int m = min(s_m, SUBCAP);

    // exact rank (top_k order) within subset
    for (int i = tid; i < m; i += 1024) {
        float si = ss[i]; int ii = sidx[i]; int r = 0;
        for (int j = 0; j < m; ++j) {
            float sj = ss[j];
            r += (sj > si) || (sj == si && sidx[j] < ii);
        }
        srank[i] = r;
    }
    __syncthreads();

    // selected (rank < K): output position = order by flat idx among selected
    for (int i = tid; i < m; i += 1024) {
        if (srank[i] < TOPK) {
            int ii = sidx[i];
            int pos = 0;
            for (int j = 0; j < m; ++j)
                pos += (srank[j] < TOPK) && (sidx[j] < ii);
            int y = ii >> 10, x = ii & (WW - 1);
            out_center[2 * pos] = y;
            out_center[2 * pos + 1] = x;
            out_valid[pos] = 1;
            ctr2[pos] = make_float2((float)y, (float)x);
            sselidx[pos] = ii;
        }
    }
    __syncthreads();

    // V < K tail: lowest non-candidate flat indices, invalid
    if (tid == 0 && V < TOPK) {
        int slot = V, t = 0, p = 0;
        while (slot < TOPK) {
            if (p < V && t == sselidx[p]) { t++; p++; }
            else {
                out_center[2 * slot] = t >> 10;
                out_center[2 * slot + 1] = t & (WW - 1);
                out_valid[slot] = 0;
                ctr2[slot] = make_float2(1e10f, 1e10f);
                t++; slot++;
            }
        }
    }
}

// ---------------- K4: nearest-center assignment + thing mask ----------------
// Exact-safe pruning (R5 masks), R7: 2D tile remap. Block = 32x8 pixel tile,
// wave = 32x2 sub-tile. Wave bbox shrinks from ~71x8 (64x1 strip) to ~39x9,
// halving the pruning annulus area -> kept centers ~40 -> ~20 (VALU-bound
// inner loop is the k4 cost). Exactness unchanged: lb/ub lemmas are per-wave
// valid for ANY wave pixel membership; ballot masks wave-uniform; kept
// centers visited in ascending k; body op-for-op identical to the reference
// (__f*_rn, no fma contraction) -> bit-exact argmin + tie order.
__global__ __launch_bounds__(256) void k4_assign(const int* __restrict__ sem,
                                                 const float* __restrict__ off,
                                                 const float2* __restrict__ ctr2,
                                                 int* __restrict__ out_inst) {
    __shared__ float2 c[TOPK];
    int tx = threadIdx.x, ty = threadIdx.y;        // block (32,8)
    int tid = ty * 32 + tx;
    if (tid < TOPK) c[tid] = ctr2[tid];
    __syncthreads();

    int x = blockIdx.x * 32 + tx;
    int y = blockIdx.y * 8 + ty;
    int p = y * WW + x;
    int s = sem[p];                                // hoist: overlap latency
    float ly = __fadd_rn((float)y, off[p]);        // offsets[0,0]
    float lx = __fadd_rn((float)x, off[HW + p]);   // offsets[0,1]

    // wave bbox of (ly,lx) — min/max are exact, no rounding introduced
    float ymin = ly, ymax = ly, xmin = lx, xmax = lx;
    #pragma unroll
    for (int mdist = 32; mdist >= 1; mdist >>= 1) {
        ymin = fminf(ymin, __shfl_xor(ymin, mdist, 64));
        ymax = fmaxf(ymax, __shfl_xor(ymax, mdist, 64));
        xmin = fminf(xmin, __shfl_xor(xmin, mdist, 64));
        xmax = fmaxf(xmax, __shfl_xor(xmax, mdist, 64));
    }

    int lane = tid & 63;
    float ub = INFINITY;
    float lbv[4];
    // lane covers centers k = r*64 + lane
    #pragma unroll
    for (int r = 0; r < 4; ++r) {
        int k = r * 64 + lane;
        float lb = INFINITY;
        float u = INFINITY;
        if (k < TOPK) {
            float2 ck = c[k];
            // far-corner bound: dyM >= |rn(cy - ly)| for all ly in [ymin,ymax]
            float dyM = fmaxf(__fsub_rn(ck.x, ymin), __fsub_rn(ymax, ck.x));
            float dxM = fmaxf(__fsub_rn(ck.y, xmin), __fsub_rn(xmax, ck.y));
            u = __fadd_rn(__fmul_rn(dyM, dyM), __fmul_rn(dxM, dxM));
            // near-corner bound: dyL <= |rn(cy - ly)| for all ly in [ymin,ymax]
            float dyL = fmaxf(0.0f, fmaxf(__fsub_rn(ck.x, ymax), __fsub_rn(ymin, ck.x)));
            float dxL = fmaxf(0.0f, fmaxf(__fsub_rn(ck.y, xmax), __fsub_rn(xmin, ck.y)));
            lb = __fadd_rn(__fmul_rn(dyL, dyL), __fmul_rn(dxL, dxL));
        }
        ub = fminf(ub, u);
        lbv[r] = lb;
    }
    #pragma unroll
    for (int mdist = 32; mdist >= 1; mdist >>= 1)
        ub = fminf(ub, __shfl_xor(ub, mdist, 64));

    // wave-uniform keep masks (bit lane of km[r] = keep center r*64+lane)
    unsigned long long km[4];
    #pragma unroll
    for (int r = 0; r < 4; ++r) km[r] = __ballot(lbv[r] <= ub);
    if (!(km[0] | km[1] | km[2] | km[3])) {        // safety net; unreachable
        km[0] = km[1] = km[2] = ~0ull; km[3] = 0xFFull;
    }

    float best = INFINITY;
    int bid = 0;
    #pragma unroll
    for (int r = 0; r < 4; ++r) {
        unsigned long long msk = km[r];
        while (msk) {                              // uniform flow, ascending k
            int k = r * 64 + __builtin_ctzll(msk);
            msk &= msk - 1;
            float2 ck = c[k];                      // uniform k -> LDS broadcast
            float dy = __fsub_rn(ck.x, ly);
            float dx = __fsub_rn(ck.y, lx);
            float d2 = __fadd_rn(__fmul_rn(dy, dy), __fmul_rn(dx, dx));
            if (d2 < best) { best = d2; bid = k; } // strict < = first-occurrence
        }
    }
    unsigned t = (unsigned)(s - 11);               // THING_LIST = 11..18
    out_inst[p] = (t <= 7u) ? (bid + 1) : 0;
}

// ---------------- launch ----------------
extern "C" void kernel_launch(void* const* d_in, const int* in_sizes, int n_in,
                              void* d_out, int out_size, void* d_ws, size_t ws_size,
                              hipStream_t stream) {
    const int* sem = (const int*)d_in[0];
    const float* hmp = (const float*)d_in[1];
    const float* off = (const float*)d_in[2];
    int* out = (int*)d_out;

    // workspace layout (~394 KB)
    char* ws = (char*)d_ws;
    int* blkcnt   = (int*)(ws);                       // 8 KB
    int2* blkpair = (int2*)(ws + 8192);               // 384 KB (score,idx)
    float2* ctr2  = (float2*)(ws + 8192 + 393216);    // 1.6 KB

    int* out_inst = out;                   // [1,H,W] int32
    int* out_center = out + HW;            // [1,K,2] int32 (y,x)
    int* out_valid = out + HW + 2 * TOPK;  // [K] 0/1

    k1_nms<<<dim3(NBX, NBY), dim3(32, 8), 0, stream>>>(hmp, blkcnt, blkpair);
    k3_select<<<1, 1024, 0, stream>>>(blkcnt, blkpair,
                                      out_center, out_valid, ctr2);
    k4_assign<<<dim3(WW / 32, HH / 8), dim3(32, 8), 0, stream>>>(sem, off, ctr2,
                                                                 out_inst);
}